// Round 7
// baseline (146.966 us; speedup 1.0000x reference)
//
#include <hip/hip_runtime.h>
#include <math.h>

#define LL 2048
#define FF 352
#define BATCH 8
#define TOPK 84
#define FPB 4                   // f-rows per score block
#define BPB (FF / FPB)          // 88 blocks per batch
#define NBINS 2048
#define BINSCALE 256.0f         // bin = score * 256, range [0,8)
#define CAPB 256                // per-block local candidate cap
#define PCAP 16384              // per-batch global candidate pool
#define CAP2 1024               // per-batch compact candidate cap
#define FILT 32                 // filter blocks per batch
#define NROWS (BATCH * 2 * FF)  // 5632
#define FL (FF * LL)            // 720896 scores per batch

// ws int/float-index layout (regions disjoint)
#define OFF_Q 64                              // 48 floats (query)
#define OFF_CNT 128                           // 8 ints: pool counters
#define OFF_CNT2 136                          // 8 ints: compact counters
#define OFF_PART 256                          // 5632 float4
#define OFF_HIST 24576                        // 8*2048 ints (ends 40960)
#define OFF_PS 49152                          // 8*16384 floats (pool scores)
#define OFF_PI (OFF_PS + BATCH * PCAP)        // 8*16384 ints  (pool indices)
#define OFF_FS 393216                         // 8*1024 floats (compact scores)
#define OFF_FI (OFF_FS + BATCH * CAP2)        // 8*1024 ints   (compact indices)

// One block per 8 rows: partial = (rowsum, x[0], x[1], x[L-1]) per row.
// Blocks 0-63 zero the global histogram; block 64 zeroes the counters.
__global__ __launch_bounds__(256) void k_rowsum(const float* __restrict__ x,
                                                float* __restrict__ ws,
                                                int* __restrict__ wsi) {
    int rb = blockIdx.x * 8;
    int tid = threadIdx.x;
    if (blockIdx.x < 64) wsi[OFF_HIST + blockIdx.x * 256 + tid] = 0;
    if (blockIdx.x == 64 && tid < 16) wsi[OFF_CNT + tid] = 0;
    __shared__ float red[8][4];
    float4 v0[8], v1[8];
    #pragma unroll
    for (int rr = 0; rr < 8; ++rr) {
        const float4* rp = (const float4*)(x + (size_t)(rb + rr) * LL);
        v0[rr] = rp[tid];
        v1[rr] = rp[tid + 256];
    }
    int lane = tid & 63, wid = tid >> 6;
    #pragma unroll
    for (int rr = 0; rr < 8; ++rr) {
        float s = v0[rr].x + v0[rr].y + v0[rr].z + v0[rr].w
                + v1[rr].x + v1[rr].y + v1[rr].z + v1[rr].w;
        for (int off = 32; off; off >>= 1) s += __shfl_down(s, off);
        if (lane == 0) red[rr][wid] = s;
    }
    __syncthreads();
    #pragma unroll
    for (int rr = 0; rr < 8; ++rr) {
        float* part = ws + OFF_PART + 4 * (rb + rr);
        if (tid == 0) {
            part[0] = red[rr][0] + red[rr][1] + red[rr][2] + red[rr][3];
            part[1] = v0[rr].x;
            part[2] = v0[rr].y;
        }
        if (tid == 255) part[3] = v1[rr].w;
    }
}

// One block per (b, 4 f-rows): query prologue, register-stencil scores
// (8 contiguous cols/thread/row), 2048-bin LDS histogram -> local top-84
// threshold -> emit ~88+ candidates to the global pool.
__global__ __launch_bounds__(256) void k_score(const float* __restrict__ x,
                                               float* __restrict__ ws,
                                               int* __restrict__ wsi) {
    __shared__ __align__(16) unsigned int hist[NBINS];
    __shared__ float4 red0[4], red1[4];
    __shared__ float sq[6];
    __shared__ int chunk[256];
    __shared__ int s_tl;
    __shared__ unsigned int s_lcnt;
    __shared__ int s_base;
    __shared__ float lps[CAPB];
    __shared__ int lpi[CAPB];
    int tid = threadIdx.x;
    int b = blockIdx.x / BPB, blk = blockIdx.x % BPB;
    int fb = blk * FPB;
    int lane = tid & 63, wid = tid >> 6;

    for (int k = 0; k < NBINS / 256; ++k) hist[tid + (k << 8)] = 0u;
    if (tid == 0) s_lcnt = 0u;

    // ---- query prologue: reduce 704 partials for this batch ----
    float4 acc0 = {0.f, 0.f, 0.f, 0.f}, acc1 = {0.f, 0.f, 0.f, 0.f};
    const float4* part = (const float4*)(ws + OFF_PART) + b * 2 * FF;
    for (int i = tid; i < 2 * FF; i += 256) {
        float4 p = part[i];
        if (i < FF) { acc0.x += p.x; acc0.y += p.y; acc0.z += p.z; acc0.w += p.w; }
        else        { acc1.x += p.x; acc1.y += p.y; acc1.z += p.z; acc1.w += p.w; }
    }
    for (int off = 32; off; off >>= 1) {
        acc0.x += __shfl_down(acc0.x, off); acc0.y += __shfl_down(acc0.y, off);
        acc0.z += __shfl_down(acc0.z, off); acc0.w += __shfl_down(acc0.w, off);
        acc1.x += __shfl_down(acc1.x, off); acc1.y += __shfl_down(acc1.y, off);
        acc1.z += __shfl_down(acc1.z, off); acc1.w += __shfl_down(acc1.w, off);
    }
    if (lane == 0) { red0[wid] = acc0; red1[wid] = acc1; }
    __syncthreads();
    if (tid == 0) {
        float A0 = 0, B0 = 0, C0 = 0, D0 = 0, A1 = 0, B1 = 0, C1 = 0, D1 = 0;
        for (int w2 = 0; w2 < 4; ++w2) {
            A0 += red0[w2].x; B0 += red0[w2].y; C0 += red0[w2].z; D0 += red0[w2].w;
            A1 += red1[w2].x; B1 += red1[w2].y; C1 += red1[w2].z; D1 += red1[w2].w;
        }
        const float inv = 1.f / (float)FL;
        sq[0] = A0 * inv;
        sq[1] = A1 * inv;
        sq[2] = (A0 - B0 + D0) * inv;
        sq[3] = (A1 - B1 + D1) * inv;
        sq[4] = (A0 - B0 - C0 + 2.f * D0) * inv;
        sq[5] = (A1 - B1 - C1 + 2.f * D1) * inv;
        if (blk == 0) for (int e = 0; e < 6; ++e) ws[OFF_Q + b * 6 + e] = sq[e];
    }
    __syncthreads();
    float q0 = sq[0], q1 = sq[1], q2 = sq[2], q3 = sq[3], q4 = sq[4], q5 = sq[5];

    // ---- scores: 8 contiguous cols per thread per f-row, kept in VGPRs ----
    float sreg[FPB][8];
    int l0 = tid * 8;
    #pragma unroll
    for (int fr = 0; fr < FPB; ++fr) {
        int f = fb + fr;
        const float* r0 = x + ((size_t)(b * 2 + 0) * FF + f) * LL;
        const float* r1 = x + ((size_t)(b * 2 + 1) * FF + f) * LL;
        float4 u0 = *(const float4*)(r0 + l0);
        float4 u1 = *(const float4*)(r0 + l0 + 4);
        float4 w0 = *(const float4*)(r1 + l0);
        float4 w1 = *(const float4*)(r1 + l0 + 4);
        float a8 = __shfl_down(u0.x, 1), a9 = __shfl_down(u0.y, 1);
        float c8 = __shfl_down(w0.x, 1), c9 = __shfl_down(w0.y, 1);
        if (lane == 63) {
            if (tid == 255) { a8 = u1.w; a9 = u1.w; c8 = w1.w; c9 = w1.w; }
            else { a8 = r0[l0 + 8]; a9 = r0[l0 + 9];
                   c8 = r1[l0 + 8]; c9 = r1[l0 + 9]; }
        }
        float a[10] = {u0.x, u0.y, u0.z, u0.w, u1.x, u1.y, u1.z, u1.w, a8, a9};
        float c[10] = {w0.x, w0.y, w0.z, w0.w, w1.x, w1.y, w1.z, w1.w, c8, c9};
        #pragma unroll
        for (int j = 0; j < 8; ++j) {
            float s = q0 * a[j] + q1 * c[j] + q2 * a[j + 1] + q3 * c[j + 1]
                    + q4 * a[j + 2] + q5 * c[j + 2];
            sreg[fr][j] = s;
            int bin = (int)(fmaxf(s, 0.f) * BINSCALE);
            bin = bin > NBINS - 1 ? NBINS - 1 : bin;
            atomicAdd(&hist[bin], 1u);
        }
    }
    __syncthreads();

    // ---- local threshold: suffix_count(tl) >= TOPK > suffix_count(tl+1) ----
    {
        int4 q = ((const int4*)hist)[tid * 2];
        int4 r = ((const int4*)hist)[tid * 2 + 1];
        chunk[tid] = q.x + q.y + q.z + q.w + r.x + r.y + r.z + r.w;
    }
    __syncthreads();
    if (tid == 0) {
        int cum = 0, c = 255;
        for (; c >= 0; --c) {
            cum += chunk[c];
            if (cum >= TOPK) break;
        }
        if (c < 0) c = 0;
        int cum2 = cum - chunk[c];
        int tl = c * 8;
        for (int bin = c * 8 + 7; bin >= c * 8; --bin) {
            cum2 += (int)hist[bin];
            if (cum2 >= TOPK) { tl = bin; break; }
        }
        s_tl = tl;
    }
    __syncthreads();
    int tl = s_tl;

    // ---- filter local candidates (superset of local top-84) into LDS ----
    #pragma unroll
    for (int fr = 0; fr < FPB; ++fr) {
        int nb = (fb + fr) * LL + l0;
        #pragma unroll
        for (int j = 0; j < 8; ++j) {
            float sv = sreg[fr][j];
            int bin = (int)(fmaxf(sv, 0.f) * BINSCALE);
            bin = bin > NBINS - 1 ? NBINS - 1 : bin;
            if (bin >= tl) {
                unsigned int p = atomicAdd(&s_lcnt, 1u);
                if (p < CAPB) { lps[p] = sv; lpi[p] = nb + j; }
            }
        }
    }
    __syncthreads();
    int lcnt = s_lcnt > CAPB ? CAPB : (int)s_lcnt;
    if (tid == 0) s_base = atomicAdd(&wsi[OFF_CNT + b], lcnt);
    __syncthreads();
    int base = s_base;
    for (int p = tid; p < lcnt; p += 256) {
        int gp = base + p;
        if (gp < PCAP) {
            ws[OFF_PS + b * PCAP + gp] = lps[p];
            wsi[OFF_PI + b * PCAP + gp] = lpi[p];
        }
    }
    // ---- flush histogram to global ----
    for (int k = 0; k < NBINS / 256; ++k) {
        int p = tid + (k << 8);
        unsigned int c = hist[p];
        if (c) atomicAdd(&wsi[OFF_HIST + b * NBINS + p], (int)c);
    }
}

// 32 blocks per batch: global threshold from hist (redundant per block),
// filter a pool slice into the compact buffer.
__global__ __launch_bounds__(256) void k_filter(float* __restrict__ ws,
                                                int* __restrict__ wsi) {
    __shared__ int chunk[256];
    __shared__ int s_t;
    int tid = threadIdx.x;
    int b = blockIdx.x / FILT, sl = blockIdx.x % FILT;
    const int* gh = wsi + OFF_HIST + b * NBINS;

    {
        int4 q = ((const int4*)gh)[tid * 2];
        int4 r = ((const int4*)gh)[tid * 2 + 1];
        chunk[tid] = q.x + q.y + q.z + q.w + r.x + r.y + r.z + r.w;
    }
    __syncthreads();
    if (tid == 0) {
        int cum = 0, c = 255;
        for (; c >= 0; --c) {
            cum += chunk[c];
            if (cum >= TOPK) break;
        }
        if (c < 0) c = 0;
        int cum2 = cum - chunk[c];
        int t = c * 8;
        for (int bin = c * 8 + 7; bin >= c * 8; --bin) {
            cum2 += gh[bin];
            if (cum2 >= TOPK) { t = bin; break; }
        }
        s_t = t;
    }
    __syncthreads();
    int t = s_t;

    int n = wsi[OFF_CNT + b];
    if (n > PCAP) n = PCAP;
    int chunkN = (n + FILT - 1) / FILT;
    int p0 = sl * chunkN;
    int p1 = p0 + chunkN; if (p1 > n) p1 = n;
    for (int p = p0 + tid; p < p1; p += 256) {
        float sv = ws[OFF_PS + b * PCAP + p];
        int bin = (int)(fmaxf(sv, 0.f) * BINSCALE);
        bin = bin > NBINS - 1 ? NBINS - 1 : bin;
        if (bin >= t) {
            int q = atomicAdd(&wsi[OFF_CNT2 + b], 1);
            if (q < CAP2) {
                ws[OFF_FS + b * CAP2 + q] = sv;
                wsi[OFF_FI + b * CAP2 + q] = wsi[OFF_PI + b * PCAP + p];
            }
        }
    }
}

// One block per batch: exact rank-select top-84 among ~88 compact candidates,
// softmax, gather, output.
__global__ __launch_bounds__(256) void k_final(const float* __restrict__ x,
                                               const float* __restrict__ wv,
                                               const float* __restrict__ ws,
                                               const int* __restrict__ wsi,
                                               float* __restrict__ out) {
    __shared__ float cs[CAP2];
    __shared__ int ci[CAP2];
    __shared__ float redm[4];
    __shared__ float den;
    __shared__ float acc[8];
    int tid = threadIdx.x;
    int b = blockIdx.x;
    int C = wsi[OFF_CNT2 + b];
    if (C > CAP2) C = CAP2;
    for (int p = tid; p < C; p += 256) {
        cs[p] = ws[OFF_FS + b * CAP2 + p];
        ci[p] = wsi[OFF_FI + b * CAP2 + p];
    }
    if (tid < 8) acc[tid] = 0.f;
    if (tid == 0) den = 0.f;
    __syncthreads();

    float m = -INFINITY;
    for (int p = tid; p < C; p += 256) m = fmaxf(m, cs[p]);
    for (int off = 32; off; off >>= 1) m = fmaxf(m, __shfl_down(m, off));
    int lane = tid & 63, wid = tid >> 6;
    if (lane == 0) redm[wid] = m;
    __syncthreads();
    float smax = fmaxf(fmaxf(redm[0], redm[1]), fmaxf(redm[2], redm[3]));

    for (int p = tid; p < C; p += 256) {
        float s = cs[p];
        int idx = ci[p];
        int rank = 0;
        for (int j = 0; j < C; ++j) {
            float sj = cs[j];
            int ij = ci[j];
            rank += (sj > s) || (sj == s && ij < idx);
        }
        if (rank < TOPK) {
            float pexp = expf(s - smax);
            atomicAdd(&den, pexp);
            int f = idx >> 11, l = idx & (LL - 1);
            int l1 = l + 1 < LL ? l + 1 : LL - 1;
            int l2 = l + 2 < LL ? l + 2 : LL - 1;
            const float* r0 = x + ((size_t)(b * 2 + 0) * FF + f) * LL;
            const float* r1 = x + ((size_t)(b * 2 + 1) * FF + f) * LL;
            atomicAdd(&acc[0], pexp * r0[l]);
            atomicAdd(&acc[1], pexp * r1[l]);
            atomicAdd(&acc[2], pexp * r0[l1]);
            atomicAdd(&acc[3], pexp * r1[l1]);
            atomicAdd(&acc[4], pexp * r0[l2]);
            atomicAdd(&acc[5], pexp * r1[l2]);
        }
    }
    __syncthreads();
    if (tid < 6) {
        float w = wv[0];
        float q = ws[OFF_Q + b * 6 + tid];
        out[b * 6 + tid] = (acc[tid] / den) * w + q * (0.5f - w);
    }
}

extern "C" void kernel_launch(void* const* d_in, const int* in_sizes, int n_in,
                              void* d_out, int out_size, void* d_ws, size_t ws_size,
                              hipStream_t stream) {
    const float* x = (const float*)d_in[0];
    const float* w = (const float*)d_in[1];
    float* out = (float*)d_out;
    float* wsf = (float*)d_ws;
    int* wsi = (int*)d_ws;

    k_rowsum<<<NROWS / 8, 256, 0, stream>>>(x, wsf, wsi);
    k_score<<<BATCH * BPB, 256, 0, stream>>>(x, wsf, wsi);
    k_filter<<<BATCH * FILT, 256, 0, stream>>>(wsf, wsi);
    k_final<<<BATCH, 256, 0, stream>>>(x, w, wsf, wsi, out);
}

// Round 9
// 144.357 us; speedup vs baseline: 1.0181x; 1.0181x over previous
//
#include <hip/hip_runtime.h>
#include <math.h>

#define LL 2048
#define FF 352
#define BATCH 8
#define TOPK 84
#define FPB 4                   // f-rows per score block
#define BPB (FF / FPB)          // 88 blocks per batch
#define NBINS 2048
#define BINSCALE 256.0f         // bin = score * 256, range [0,8)
#define CAPB 256                // per-block local candidate cap
#define PCAP 16384              // per-batch global candidate pool
#define CAP2 1024               // per-batch compact candidate cap
#define FILT 32                 // filter blocks per batch
#define NROWS (BATCH * 2 * FF)  // 5632
#define FL (FF * LL)            // 720896 scores per batch

// ws int/float-index layout (regions disjoint)
#define OFF_Q 64                              // 48 floats (query)
#define OFF_CNT 128                           // 8 ints: pool counters
#define OFF_CNT2 136                          // 8 ints: compact counters
#define OFF_PART 256                          // 5632 float4
#define OFF_HIST 24576                        // 8*2048 ints (ends 40960)
#define OFF_PS 49152                          // 8*16384 floats (pool scores)
#define OFF_PI (OFF_PS + BATCH * PCAP)        // 8*16384 ints  (pool indices)
#define OFF_FS 393216                         // 8*1024 floats (compact scores)
#define OFF_FI (OFF_FS + BATCH * CAP2)        // 8*1024 ints   (compact indices)

// One block per (b,ch,f) row: partial = (rowsum, x[0], x[1], x[L-1]).
// Blocks 0-63 zero the global histogram; block 64 zeroes the counters.
__global__ __launch_bounds__(256) void k_rowsum(const float* __restrict__ x,
                                                float* __restrict__ ws,
                                                int* __restrict__ wsi) {
    int r = blockIdx.x;              // (b*2+ch)*352 + f
    int tid = threadIdx.x;
    if (r < 64) wsi[OFF_HIST + r * 256 + tid] = 0;
    if (r == 64 && tid < 16) wsi[OFF_CNT + tid] = 0;
    const float4* rp = (const float4*)(x + (size_t)r * LL);
    float4 v0 = rp[tid];
    float4 v1 = rp[tid + 256];
    float s = v0.x + v0.y + v0.z + v0.w + v1.x + v1.y + v1.z + v1.w;
    for (int off = 32; off; off >>= 1) s += __shfl_down(s, off);
    __shared__ float red[4];
    int lane = tid & 63, wid = tid >> 6;
    if (lane == 0) red[wid] = s;
    __syncthreads();
    float* part = ws + OFF_PART + 4 * r;
    if (tid == 0) {
        part[0] = red[0] + red[1] + red[2] + red[3];
        part[1] = v0.x;
        part[2] = v0.y;
    }
    if (tid == 255) part[3] = v1.w;
}

// One block per (b, 4 f-rows): query prologue, register-stencil scores,
// 2048-bin LDS histogram -> local top-84 threshold -> emit ~88 candidates.
__global__ __launch_bounds__(256) void k_score(const float* __restrict__ x,
                                               float* __restrict__ ws,
                                               int* __restrict__ wsi) {
    __shared__ __align__(16) unsigned int hist[NBINS];
    __shared__ float4 red0[4], red1[4];
    __shared__ float sq[6];
    __shared__ int chunk[256];
    __shared__ int s_tl;
    __shared__ unsigned int s_lcnt;
    __shared__ int s_base;
    __shared__ float lps[CAPB];
    __shared__ int lpi[CAPB];
    int tid = threadIdx.x;
    int b = blockIdx.x / BPB, blk = blockIdx.x % BPB;
    int fb = blk * FPB;
    int lane = tid & 63, wid = tid >> 6;

    for (int k = 0; k < NBINS / 256; ++k) hist[tid + (k << 8)] = 0u;
    if (tid == 0) s_lcnt = 0u;

    // ---- query prologue: reduce 704 partials for this batch ----
    float4 acc0 = {0.f, 0.f, 0.f, 0.f}, acc1 = {0.f, 0.f, 0.f, 0.f};
    const float4* part = (const float4*)(ws + OFF_PART) + b * 2 * FF;
    for (int i = tid; i < 2 * FF; i += 256) {
        float4 p = part[i];
        if (i < FF) { acc0.x += p.x; acc0.y += p.y; acc0.z += p.z; acc0.w += p.w; }
        else        { acc1.x += p.x; acc1.y += p.y; acc1.z += p.z; acc1.w += p.w; }
    }
    for (int off = 32; off; off >>= 1) {
        acc0.x += __shfl_down(acc0.x, off); acc0.y += __shfl_down(acc0.y, off);
        acc0.z += __shfl_down(acc0.z, off); acc0.w += __shfl_down(acc0.w, off);
        acc1.x += __shfl_down(acc1.x, off); acc1.y += __shfl_down(acc1.y, off);
        acc1.z += __shfl_down(acc1.z, off); acc1.w += __shfl_down(acc1.w, off);
    }
    if (lane == 0) { red0[wid] = acc0; red1[wid] = acc1; }
    __syncthreads();
    if (tid == 0) {
        float A0 = 0, B0 = 0, C0 = 0, D0 = 0, A1 = 0, B1 = 0, C1 = 0, D1 = 0;
        for (int w2 = 0; w2 < 4; ++w2) {
            A0 += red0[w2].x; B0 += red0[w2].y; C0 += red0[w2].z; D0 += red0[w2].w;
            A1 += red1[w2].x; B1 += red1[w2].y; C1 += red1[w2].z; D1 += red1[w2].w;
        }
        const float inv = 1.f / (float)FL;
        sq[0] = A0 * inv;
        sq[1] = A1 * inv;
        sq[2] = (A0 - B0 + D0) * inv;
        sq[3] = (A1 - B1 + D1) * inv;
        sq[4] = (A0 - B0 - C0 + 2.f * D0) * inv;
        sq[5] = (A1 - B1 - C1 + 2.f * D1) * inv;
        if (blk == 0) for (int e = 0; e < 6; ++e) ws[OFF_Q + b * 6 + e] = sq[e];
    }
    __syncthreads();
    float q0 = sq[0], q1 = sq[1], q2 = sq[2], q3 = sq[3], q4 = sq[4], q5 = sq[5];

    // ---- scores: register stencil, 32 scores/thread kept in VGPRs ----
    float4 sreg[8];
    #pragma unroll
    for (int fr = 0; fr < FPB; ++fr) {
        int f = fb + fr;
        const float* r0 = x + ((size_t)(b * 2 + 0) * FF + f) * LL;
        const float* r1 = x + ((size_t)(b * 2 + 1) * FF + f) * LL;
        #pragma unroll
        for (int h = 0; h < 2; ++h) {
            int l0 = (h << 10) + tid * 4;
            float4 u = *(const float4*)(r0 + l0);
            float4 v = *(const float4*)(r1 + l0);
            float a4 = __shfl_down(u.x, 1), a5 = __shfl_down(u.y, 1);
            float b4 = __shfl_down(v.x, 1), b5 = __shfl_down(v.y, 1);
            if (lane == 63) {
                if (l0 == LL - 4) { a4 = u.w; a5 = u.w; b4 = v.w; b5 = v.w; }
                else { a4 = r0[l0 + 4]; a5 = r0[l0 + 5];
                       b4 = r1[l0 + 4]; b5 = r1[l0 + 5]; }
            }
            float4 s;
            s.x = q0 * u.x + q1 * v.x + q2 * u.y + q3 * v.y + q4 * u.z + q5 * v.z;
            s.y = q0 * u.y + q1 * v.y + q2 * u.z + q3 * v.z + q4 * u.w + q5 * v.w;
            s.z = q0 * u.z + q1 * v.z + q2 * u.w + q3 * v.w + q4 * a4 + q5 * b4;
            s.w = q0 * u.w + q1 * v.w + q2 * a4 + q3 * b4 + q4 * a5 + q5 * b5;
            sreg[fr * 2 + h] = s;
            #pragma unroll
            for (int j = 0; j < 4; ++j) {
                float sv = j == 0 ? s.x : (j == 1 ? s.y : (j == 2 ? s.z : s.w));
                int bin = (int)(fmaxf(sv, 0.f) * BINSCALE);
                bin = bin > NBINS - 1 ? NBINS - 1 : bin;
                atomicAdd(&hist[bin], 1u);
            }
        }
    }
    __syncthreads();

    // ---- local threshold: suffix_count(tl) >= TOPK > suffix_count(tl+1) ----
    {
        int4 q = ((const int4*)hist)[tid * 2];
        int4 r = ((const int4*)hist)[tid * 2 + 1];
        chunk[tid] = q.x + q.y + q.z + q.w + r.x + r.y + r.z + r.w;
    }
    __syncthreads();
    if (tid == 0) {
        int cum = 0, c = 255;
        for (; c >= 0; --c) {
            cum += chunk[c];
            if (cum >= TOPK) break;
        }
        if (c < 0) c = 0;
        int cum2 = cum - chunk[c];
        int tl = c * 8;
        for (int bin = c * 8 + 7; bin >= c * 8; --bin) {
            cum2 += (int)hist[bin];
            if (cum2 >= TOPK) { tl = bin; break; }
        }
        s_tl = tl;
    }
    __syncthreads();
    int tl = s_tl;

    // ---- filter local candidates (superset of local top-84) into LDS ----
    #pragma unroll
    for (int fr = 0; fr < FPB; ++fr) {
        #pragma unroll
        for (int h = 0; h < 2; ++h) {
            float4 s = sreg[fr * 2 + h];
            int nb = (fb + fr) * LL + (h << 10) + tid * 4;
            #pragma unroll
            for (int j = 0; j < 4; ++j) {
                float sv = j == 0 ? s.x : (j == 1 ? s.y : (j == 2 ? s.z : s.w));
                int bin = (int)(fmaxf(sv, 0.f) * BINSCALE);
                bin = bin > NBINS - 1 ? NBINS - 1 : bin;
                if (bin >= tl) {
                    unsigned int p = atomicAdd(&s_lcnt, 1u);
                    if (p < CAPB) { lps[p] = sv; lpi[p] = nb + j; }
                }
            }
        }
    }
    __syncthreads();
    int lcnt = s_lcnt > CAPB ? CAPB : (int)s_lcnt;
    if (tid == 0) s_base = atomicAdd(&wsi[OFF_CNT + b], lcnt);
    __syncthreads();
    int base = s_base;
    for (int p = tid; p < lcnt; p += 256) {
        int gp = base + p;
        if (gp < PCAP) {
            ws[OFF_PS + b * PCAP + gp] = lps[p];
            wsi[OFF_PI + b * PCAP + gp] = lpi[p];
        }
    }
    // ---- flush histogram to global ----
    for (int k = 0; k < NBINS / 256; ++k) {
        int p = tid + (k << 8);
        unsigned int c = hist[p];
        if (c) atomicAdd(&wsi[OFF_HIST + b * NBINS + p], (int)c);
    }
}

// 32 blocks per batch: global threshold from hist (redundant per block),
// filter a pool slice into the compact buffer.
__global__ __launch_bounds__(256) void k_filter(float* __restrict__ ws,
                                                int* __restrict__ wsi) {
    __shared__ int chunk[256];
    __shared__ int s_t;
    int tid = threadIdx.x;
    int b = blockIdx.x / FILT, sl = blockIdx.x % FILT;
    const int* gh = wsi + OFF_HIST + b * NBINS;

    {
        int4 q = ((const int4*)gh)[tid * 2];
        int4 r = ((const int4*)gh)[tid * 2 + 1];
        chunk[tid] = q.x + q.y + q.z + q.w + r.x + r.y + r.z + r.w;
    }
    __syncthreads();
    if (tid == 0) {
        int cum = 0, c = 255;
        for (; c >= 0; --c) {
            cum += chunk[c];
            if (cum >= TOPK) break;
        }
        if (c < 0) c = 0;
        int cum2 = cum - chunk[c];
        int t = c * 8;
        for (int bin = c * 8 + 7; bin >= c * 8; --bin) {
            cum2 += gh[bin];
            if (cum2 >= TOPK) { t = bin; break; }
        }
        s_t = t;
    }
    __syncthreads();
    int t = s_t;

    int n = wsi[OFF_CNT + b];
    if (n > PCAP) n = PCAP;
    int chunkN = (n + FILT - 1) / FILT;
    int p0 = sl * chunkN;
    int p1 = p0 + chunkN; if (p1 > n) p1 = n;
    for (int p = p0 + tid; p < p1; p += 256) {
        float sv = ws[OFF_PS + b * PCAP + p];
        int bin = (int)(fmaxf(sv, 0.f) * BINSCALE);
        bin = bin > NBINS - 1 ? NBINS - 1 : bin;
        if (bin >= t) {
            int q = atomicAdd(&wsi[OFF_CNT2 + b], 1);
            if (q < CAP2) {
                ws[OFF_FS + b * CAP2 + q] = sv;
                wsi[OFF_FI + b * CAP2 + q] = wsi[OFF_PI + b * PCAP + p];
            }
        }
    }
}

// One block per batch: exact rank-select top-84 among ~88 compact candidates,
// softmax, gather, output.
__global__ __launch_bounds__(256) void k_final(const float* __restrict__ x,
                                               const float* __restrict__ wv,
                                               const float* __restrict__ ws,
                                               const int* __restrict__ wsi,
                                               float* __restrict__ out) {
    __shared__ float cs[CAP2];
    __shared__ int ci[CAP2];
    __shared__ float redm[4];
    __shared__ float den;
    __shared__ float acc[8];
    int tid = threadIdx.x;
    int b = blockIdx.x;
    int C = wsi[OFF_CNT2 + b];
    if (C > CAP2) C = CAP2;
    for (int p = tid; p < C; p += 256) {
        cs[p] = ws[OFF_FS + b * CAP2 + p];
        ci[p] = wsi[OFF_FI + b * CAP2 + p];
    }
    if (tid < 8) acc[tid] = 0.f;
    if (tid == 0) den = 0.f;
    __syncthreads();

    float m = -INFINITY;
    for (int p = tid; p < C; p += 256) m = fmaxf(m, cs[p]);
    for (int off = 32; off; off >>= 1) m = fmaxf(m, __shfl_down(m, off));
    int lane = tid & 63, wid = tid >> 6;
    if (lane == 0) redm[wid] = m;
    __syncthreads();
    float smax = fmaxf(fmaxf(redm[0], redm[1]), fmaxf(redm[2], redm[3]));

    for (int p = tid; p < C; p += 256) {
        float s = cs[p];
        int idx = ci[p];
        int rank = 0;
        for (int j = 0; j < C; ++j) {
            float sj = cs[j];
            int ij = ci[j];
            rank += (sj > s) || (sj == s && ij < idx);
        }
        if (rank < TOPK) {
            float pexp = expf(s - smax);
            atomicAdd(&den, pexp);
            int f = idx >> 11, l = idx & (LL - 1);
            int l1 = l + 1 < LL ? l + 1 : LL - 1;
            int l2 = l + 2 < LL ? l + 2 : LL - 1;
            const float* r0 = x + ((size_t)(b * 2 + 0) * FF + f) * LL;
            const float* r1 = x + ((size_t)(b * 2 + 1) * FF + f) * LL;
            atomicAdd(&acc[0], pexp * r0[l]);
            atomicAdd(&acc[1], pexp * r1[l]);
            atomicAdd(&acc[2], pexp * r0[l1]);
            atomicAdd(&acc[3], pexp * r1[l1]);
            atomicAdd(&acc[4], pexp * r0[l2]);
            atomicAdd(&acc[5], pexp * r1[l2]);
        }
    }
    __syncthreads();
    if (tid < 6) {
        float w = wv[0];
        float q = ws[OFF_Q + b * 6 + tid];
        out[b * 6 + tid] = (acc[tid] / den) * w + q * (0.5f - w);
    }
}

extern "C" void kernel_launch(void* const* d_in, const int* in_sizes, int n_in,
                              void* d_out, int out_size, void* d_ws, size_t ws_size,
                              hipStream_t stream) {
    const float* x = (const float*)d_in[0];
    const float* w = (const float*)d_in[1];
    float* out = (float*)d_out;
    float* wsf = (float*)d_ws;
    int* wsi = (int*)d_ws;

    k_rowsum<<<NROWS, 256, 0, stream>>>(x, wsf, wsi);
    k_score<<<BATCH * BPB, 256, 0, stream>>>(x, wsf, wsi);
    k_filter<<<BATCH * FILT, 256, 0, stream>>>(wsf, wsi);
    k_final<<<BATCH, 256, 0, stream>>>(x, w, wsf, wsi, out);
}